// Round 1
// baseline (430.844 us; speedup 1.0000x reference)
//
#include <hip/hip_runtime.h>

// ---------------- problem constants ----------------
#define B_   2
#define S_   2048
#define D_   2048
#define H_   32
#define KV_  8
#define HD_  64
#define TOK_ (B_*S_)   // 4096
#define NQKV_ 3072     // 2048 q + 512 k + 512 v

typedef __attribute__((ext_vector_type(8))) short short8;
typedef __attribute__((ext_vector_type(4))) float f32x4;

// ---------------- ws layout (bytes) ----------------
#define OFF_XB   ((size_t)0)                            // bf16 x        [4096][2048]  16.8 MB
#define OFF_WQKV (OFF_XB   + (size_t)TOK_*D_*2)         // bf16 Wqkv^T   [3072][2048]  12.6 MB
#define OFF_WO   (OFF_WQKV + (size_t)NQKV_*D_*2)        // bf16 Wo^T     [2048][2048]   8.4 MB
#define OFF_QKV  (OFF_WO   + (size_t)D_*D_*2)           // bf16 qkv      [4096][3072]  25.2 MB
#define OFF_VT   (OFF_QKV  + (size_t)TOK_*NQKV_*2)      // bf16 v^T      [2][8][64][2048] 4.2 MB
#define OFF_AO   (OFF_VT   + (size_t)B_*KV_*HD_*S_*2)   // bf16 attnout  [4096][2048]  16.8 MB
#define OFF_TAB  (OFF_AO   + (size_t)TOK_*D_*2)         // float2 rope   [2048][32]     0.5 MB

__device__ __forceinline__ unsigned short f2bfu(float f) {   // RNE f32->bf16
  unsigned int x = __float_as_uint(f);
  x += 0x7fffu + ((x >> 16) & 1u);
  return (unsigned short)(x >> 16);
}
__device__ __forceinline__ float bf2f(unsigned short u) {
  return __uint_as_float(((unsigned int)u) << 16);
}
__device__ __forceinline__ void gld16(const void* g, void* l) {
  __builtin_amdgcn_global_load_lds((const __attribute__((address_space(1))) void*)g,
                                   (__attribute__((address_space(3))) void*)l, 16, 0, 0);
}

// ---------------- rope table: [s][j] -> (cos, sin), j<32 ----------------
__global__ __launch_bounds__(256) void ropetab_k(float2* tab) {
  int i = blockIdx.x * 256 + threadIdx.x;       // 2048*32 = 65536
  int s = i >> 5, j = i & 31;
  // inv_freq = 10000^(-j/32) = 2^(-j * log2(10000)/32)
  float inv = exp2f(-(float)j * (13.287712379549449f / 32.0f));
  float ang = (float)s * inv;
  tab[i] = make_float2(cosf(ang), sinf(ang));
}

// ---------------- x f32 -> bf16 ----------------
__global__ __launch_bounds__(256) void cvtx_k(const float4* __restrict__ x, ushort4* __restrict__ xb) {
  int i = blockIdx.x * 256 + threadIdx.x;       // 2097152
  float4 f = x[i];
  ushort4 o;
  o.x = f2bfu(f.x); o.y = f2bfu(f.y); o.z = f2bfu(f.z); o.w = f2bfu(f.w);
  xb[i] = o;
}

// ---------------- weight transpose+cvt: in f32 [2048][N] -> out bf16 [N][2048] ----------------
__global__ __launch_bounds__(256) void wtrans_k(const float* __restrict__ in, unsigned short* __restrict__ out, int N) {
  __shared__ float tile[32][33];
  int n0 = blockIdx.x * 32, k0 = blockIdx.y * 32;
  int tx = threadIdx.x, ty = threadIdx.y;       // 32 x 8
#pragma unroll
  for (int i = 0; i < 4; ++i)
    tile[ty + 8*i][tx] = in[(size_t)(k0 + ty + 8*i) * N + n0 + tx];
  __syncthreads();
#pragma unroll
  for (int i = 0; i < 4; ++i)
    out[(size_t)(n0 + ty + 8*i) * 2048 + k0 + tx] = f2bfu(tile[tx][ty + 8*i]);
}

// ---------------- GEMM: C[M][N] = A[M][K] * Bt[N][K]^T  (bf16 in, f32 acc) ----------------
// 128x128 tile, BK=32, 256 thr = 4 waves (2x2), each wave 64x64 (4x4 of 16x16x32)
template<int OUTF32>
__global__ __launch_bounds__(256) void gemm_bt(const unsigned short* __restrict__ A,
                                               const unsigned short* __restrict__ Bt,
                                               void* __restrict__ Cout, int M, int N, int K) {
  __shared__ unsigned short Al[2][128][32];
  __shared__ unsigned short Bl[2][128][32];
  int tid = threadIdx.x, lane = tid & 63, w = tid >> 6;
  int lr = lane & 15, lg = lane >> 4;
  int wr = w >> 1, wc = w & 1;
  int m0 = blockIdx.y * 128, n0 = blockIdx.x * 128;
  int trow = tid >> 2, tseg = tid & 3;          // 64 rows x 4 segs of 16B per shot

  auto stage = [&](int buf, int kt) {
    const unsigned short* ga0 = A + (size_t)(m0 + trow) * K + kt * 32 + tseg * 8;
    gld16(ga0, &Al[buf][trow][tseg * 8]);
    const unsigned short* ga1 = A + (size_t)(m0 + 64 + trow) * K + kt * 32 + tseg * 8;
    gld16(ga1, &Al[buf][64 + trow][tseg * 8]);
    const unsigned short* gb0 = Bt + (size_t)(n0 + trow) * K + kt * 32 + tseg * 8;
    gld16(gb0, &Bl[buf][trow][tseg * 8]);
    const unsigned short* gb1 = Bt + (size_t)(n0 + 64 + trow) * K + kt * 32 + tseg * 8;
    gld16(gb1, &Bl[buf][64 + trow][tseg * 8]);
  };

  f32x4 zero4 = {0.f, 0.f, 0.f, 0.f};
  f32x4 acc[4][4];
#pragma unroll
  for (int mi = 0; mi < 4; ++mi)
#pragma unroll
    for (int ni = 0; ni < 4; ++ni) acc[mi][ni] = zero4;

  int nk = K >> 5;
  stage(0, 0);
  int buf = 0;
  for (int kt = 0; kt < nk; ++kt) {
    __syncthreads();                      // drains vmcnt (stage of buf) + prev ds reads
    if (kt + 1 < nk) stage(buf ^ 1, kt + 1);
    short8 af[4], bfr[4];
#pragma unroll
    for (int i = 0; i < 4; ++i) {
      af[i]  = *(const short8*)&Al[buf][64 * wr + 16 * i + lr][lg * 8];
      bfr[i] = *(const short8*)&Bl[buf][64 * wc + 16 * i + lr][lg * 8];
    }
#pragma unroll
    for (int mi = 0; mi < 4; ++mi)
#pragma unroll
      for (int ni = 0; ni < 4; ++ni)
        acc[mi][ni] = __builtin_amdgcn_mfma_f32_16x16x32_bf16(af[mi], bfr[ni], acc[mi][ni], 0, 0, 0);
    buf ^= 1;
  }
  // epilogue: C/D layout col=lane&15, row=(lane>>4)*4+r  [m89-verified]
#pragma unroll
  for (int mi = 0; mi < 4; ++mi)
#pragma unroll
    for (int ni = 0; ni < 4; ++ni)
#pragma unroll
      for (int r = 0; r < 4; ++r) {
        int row = m0 + 64 * wr + 16 * mi + lg * 4 + r;
        int col = n0 + 64 * wc + 16 * ni + lr;
        float v = acc[mi][ni][r];
        if (OUTF32) ((float*)Cout)[(size_t)row * N + col] = v;
        else ((unsigned short*)Cout)[(size_t)row * N + col] = f2bfu(v);
      }
}

// ---------------- RoPE in-place on q,k columns of qkv ----------------
__global__ __launch_bounds__(256) void rope_k(unsigned short* __restrict__ qkv, const float2* __restrict__ tab) {
  int idx = blockIdx.x * 256 + threadIdx.x;    // TOK_*1280 = 5242880
  int tok = idx / 1280, r = idx % 1280;
  int col, j;
  if (r < 1024) { j = r & 31; col = (r >> 5) * 64 + j; }                     // q: head r>>5
  else { int rr = r - 1024; j = rr & 31; col = 2048 + (rr >> 5) * 64 + j; }  // k: kv head
  int s = tok & (S_ - 1);
  float2 cs = tab[s * 32 + j];
  unsigned short* p = qkv + (size_t)tok * NQKV_ + col;
  float a = bf2f(p[0]), b = bf2f(p[32]);
  p[0]  = f2bfu(a * cs.x - b * cs.y);
  p[32] = f2bfu(b * cs.x + a * cs.y);
}

// ---------------- V -> V^T relayout: qkv v-cols -> vt[b][kv][d][s] ----------------
__global__ __launch_bounds__(256) void vtrans_k(const unsigned short* __restrict__ qkv, unsigned short* __restrict__ vt) {
  __shared__ unsigned short tile[32][33];
  int s0 = blockIdx.x * 32;
  int y0 = blockIdx.y * 32;                 // global vt row = (b*KV+kv)*64 + d
  int bkv = y0 >> 6, d0 = y0 & 63;
  int b = bkv >> 3, kv = bkv & 7;
  int tx = threadIdx.x, ty = threadIdx.y;
#pragma unroll
  for (int i = 0; i < 4; ++i)
    tile[ty + 8*i][tx] = qkv[(size_t)(b * S_ + s0 + ty + 8*i) * NQKV_ + 2560 + kv * 64 + d0 + tx];
  __syncthreads();
#pragma unroll
  for (int i = 0; i < 4; ++i)
    vt[(size_t)(y0 + ty + 8*i) * (size_t)S_ + s0 + tx] = tile[tx][ty + 8*i];
}

// ---------------- flash attention ----------------
// grid (B*H=64, S/64=32); 256 thr = 4 waves, wave w owns q-rows [q0+16w, q0+16w+16)
__global__ __launch_bounds__(256) void attn_k(const unsigned short* __restrict__ qkv,
                                              const unsigned short* __restrict__ vt,
                                              unsigned short* __restrict__ ao) {
  __shared__ unsigned short Kl[2][64][64];
  __shared__ unsigned short Vl[2][64][64];   // V^T chunk: [d][local key]
  __shared__ unsigned short Pl[64][64];      // probs, wave-private rows
  int bh = blockIdx.x, b = bh >> 5, h = bh & 31, kvh = h >> 2;
  int q0 = blockIdx.y * 64;
  int tid = threadIdx.x, w = tid >> 6, lane = tid & 63;
  int lr = lane & 15, lg = lane >> 4;

  // Q fragments held in registers (a-frag row = lane&15, k consecutive)
  const unsigned short* qp = qkv + (size_t)(b * S_ + q0 + 16 * w + lr) * NQKV_ + h * 64 + lg * 8;
  short8 qa0 = *(const short8*)qp;
  short8 qa1 = *(const short8*)(qp + 32);

  const unsigned short* kbase = qkv + (size_t)(b * S_) * NQKV_ + 2048 + kvh * 64;
  const unsigned short* vbase = vt + (size_t)(b * KV_ + kvh) * 64 * S_;
  int srow = tid >> 3, sseg = tid & 7;       // 32 rows x 8 segs per 4KB shot

  auto stageKV = [&](int buf, int kv0) {
#pragma unroll
    for (int sh = 0; sh < 2; ++sh) {
      const unsigned short* gk = kbase + (size_t)(kv0 + 32 * sh + srow) * NQKV_ + sseg * 8;
      gld16(gk, &Kl[buf][32 * sh + srow][sseg * 8]);
      const unsigned short* gv = vbase + (size_t)(32 * sh + srow) * S_ + kv0 + sseg * 8;
      gld16(gv, &Vl[buf][32 * sh + srow][sseg * 8]);
    }
  };

  f32x4 zero4 = {0.f, 0.f, 0.f, 0.f};
  f32x4 o[4]; float rmax[4], rsum[4];
#pragma unroll
  for (int i = 0; i < 4; ++i) { o[i] = zero4; rmax[i] = -1e30f; rsum[i] = 0.f; }

  stageKV(0, 0);
  int buf = 0;
  for (int it = 0; it < S_ / 64; ++it) {
    __syncthreads();
    if (it + 1 < S_ / 64) stageKV(buf ^ 1, (it + 1) * 64);

    // --- S = Q K^T * 0.125 ---
    f32x4 sc[4];
#pragma unroll
    for (int c = 0; c < 4; ++c) {
      short8 kb0 = *(const short8*)&Kl[buf][16 * c + lr][lg * 8];
      short8 kb1 = *(const short8*)&Kl[buf][16 * c + lr][32 + lg * 8];
      f32x4 z = zero4;
      z = __builtin_amdgcn_mfma_f32_16x16x32_bf16(qa0, kb0, z, 0, 0, 0);
      z = __builtin_amdgcn_mfma_f32_16x16x32_bf16(qa1, kb1, z, 0, 0, 0);
#pragma unroll
      for (int r = 0; r < 4; ++r) z[r] *= 0.125f;
      sc[c] = z;
    }

    // --- online softmax (rows = lg*4+r, replicated across the 16-lane col group) ---
    float ml[4];
#pragma unroll
    for (int r = 0; r < 4; ++r)
      ml[r] = fmaxf(fmaxf(sc[0][r], sc[1][r]), fmaxf(sc[2][r], sc[3][r]));
#pragma unroll
    for (int xm = 1; xm <= 8; xm <<= 1)
#pragma unroll
      for (int r = 0; r < 4; ++r) ml[r] = fmaxf(ml[r], __shfl_xor(ml[r], xm));
    float corr[4];
#pragma unroll
    for (int r = 0; r < 4; ++r) {
      float mn = fmaxf(rmax[r], ml[r]);
      corr[r] = __expf(rmax[r] - mn);
      rmax[r] = mn;
    }
#pragma unroll
    for (int dt = 0; dt < 4; ++dt)
#pragma unroll
      for (int r = 0; r < 4; ++r) o[dt][r] *= corr[r];
    float rs[4];
#pragma unroll
    for (int r = 0; r < 4; ++r) rs[r] = 0.f;
#pragma unroll
    for (int c = 0; c < 4; ++c)
#pragma unroll
      for (int r = 0; r < 4; ++r) {
        float p = __expf(sc[c][r] - rmax[r]);
        sc[c][r] = p;
        rs[r] += p;
      }
#pragma unroll
    for (int xm = 1; xm <= 8; xm <<= 1)
#pragma unroll
      for (int r = 0; r < 4; ++r) rs[r] += __shfl_xor(rs[r], xm);
#pragma unroll
    for (int r = 0; r < 4; ++r) rsum[r] = rsum[r] * corr[r] + rs[r];

    // --- P -> LDS bf16 (wave-private rows; same-wave DS ops are in-order) ---
#pragma unroll
    for (int c = 0; c < 4; ++c)
#pragma unroll
      for (int r = 0; r < 4; ++r)
        Pl[16 * w + 4 * lg + r][16 * c + lr] = f2bfu(sc[c][r]);

    // --- O += P V ---
    short8 pa0 = *(const short8*)&Pl[16 * w + lr][lg * 8];
    short8 pa1 = *(const short8*)&Pl[16 * w + lr][32 + lg * 8];
#pragma unroll
    for (int dt = 0; dt < 4; ++dt) {
      short8 vb0 = *(const short8*)&Vl[buf][16 * dt + lr][lg * 8];
      short8 vb1 = *(const short8*)&Vl[buf][16 * dt + lr][32 + lg * 8];
      o[dt] = __builtin_amdgcn_mfma_f32_16x16x32_bf16(pa0, vb0, o[dt], 0, 0, 0);
      o[dt] = __builtin_amdgcn_mfma_f32_16x16x32_bf16(pa1, vb1, o[dt], 0, 0, 0);
    }
    buf ^= 1;
  }

  // --- epilogue: O / rowsum -> attn_out[b][s][h][d] ---
#pragma unroll
  for (int r = 0; r < 4; ++r) {
    float inv = 1.f / rsum[r];
    int row = q0 + 16 * w + 4 * lg + r;
#pragma unroll
    for (int dt = 0; dt < 4; ++dt)
      ao[(size_t)(b * S_ + row) * D_ + h * 64 + 16 * dt + lr] = f2bfu(o[dt][r] * inv);
  }
}

// ---------------- launch ----------------
extern "C" void kernel_launch(void* const* d_in, const int* in_sizes, int n_in,
                              void* d_out, int out_size, void* d_ws, size_t ws_size,
                              hipStream_t stream) {
  const float* x  = (const float*)d_in[0];
  const float* Wq = (const float*)d_in[1];
  const float* Wk = (const float*)d_in[2];
  const float* Wv = (const float*)d_in[3];
  const float* Wo = (const float*)d_in[4];

  char* ws = (char*)d_ws;
  unsigned short* xb    = (unsigned short*)(ws + OFF_XB);
  unsigned short* wqkvt = (unsigned short*)(ws + OFF_WQKV);
  unsigned short* wot   = (unsigned short*)(ws + OFF_WO);
  unsigned short* qkv   = (unsigned short*)(ws + OFF_QKV);
  unsigned short* vt    = (unsigned short*)(ws + OFF_VT);
  unsigned short* ao    = (unsigned short*)(ws + OFF_AO);
  float2*         tab   = (float2*)(ws + OFF_TAB);

  ropetab_k<<<dim3(256), dim3(256), 0, stream>>>(tab);
  cvtx_k<<<dim3((TOK_*D_/4)/256), dim3(256), 0, stream>>>((const float4*)x, (ushort4*)xb);
  wtrans_k<<<dim3(64, 64), dim3(32, 8), 0, stream>>>(Wq, wqkvt, 2048);
  wtrans_k<<<dim3(16, 64), dim3(32, 8), 0, stream>>>(Wk, wqkvt + (size_t)2048 * 2048, 512);
  wtrans_k<<<dim3(16, 64), dim3(32, 8), 0, stream>>>(Wv, wqkvt + (size_t)2560 * 2048, 512);
  wtrans_k<<<dim3(64, 64), dim3(32, 8), 0, stream>>>(Wo, wot, 2048);

  gemm_bt<0><<<dim3(NQKV_/128, TOK_/128), dim3(256), 0, stream>>>(xb, wqkvt, (void*)qkv, TOK_, NQKV_, D_);
  rope_k<<<dim3(TOK_ * 1280 / 256), dim3(256), 0, stream>>>(qkv, tab);
  vtrans_k<<<dim3(S_/32, (B_*KV_*HD_)/32), dim3(32, 8), 0, stream>>>(qkv, vt);
  attn_k<<<dim3(B_*H_, S_/64), dim3(256), 0, stream>>>(qkv, vt, ao);
  gemm_bt<1><<<dim3(D_/128, TOK_/128), dim3(256), 0, stream>>>(ao, wot, d_out, TOK_, D_, D_);
}

// Round 2
// 306.989 us; speedup vs baseline: 1.4035x; 1.4035x over previous
//
#include <hip/hip_runtime.h>

// ---------------- problem constants ----------------
#define B_   2
#define S_   2048
#define D_   2048
#define H_   32
#define KV_  8
#define HD_  64
#define TOK_ (B_*S_)   // 4096
#define NQKV_ 3072     // 2048 q + 512 k + 512 v

typedef __attribute__((ext_vector_type(8))) short short8;
typedef __attribute__((ext_vector_type(4))) float f32x4;

// ---------------- ws layout (bytes) ----------------
#define OFF_XB   ((size_t)0)                            // bf16 x        [4096][2048]  16.8 MB
#define OFF_WQKV (OFF_XB   + (size_t)TOK_*D_*2)         // bf16 Wqkv^T   [3072][2048]  12.6 MB
#define OFF_WO   (OFF_WQKV + (size_t)NQKV_*D_*2)        // bf16 Wo^T     [2048][2048]   8.4 MB
#define OFF_QKV  (OFF_WO   + (size_t)D_*D_*2)           // bf16 qkv      [4096][3072]  25.2 MB
#define OFF_VT   (OFF_QKV  + (size_t)TOK_*NQKV_*2)      // bf16 v^T      [2][8][64][2048] 4.2 MB
#define OFF_AO   (OFF_VT   + (size_t)B_*KV_*HD_*S_*2)   // bf16 attnout  [4096][2048]  16.8 MB
#define OFF_TAB  (OFF_AO   + (size_t)TOK_*D_*2)         // float2 rope   [2048][32]     0.5 MB

__device__ __forceinline__ unsigned short f2bfu(float f) {   // RNE f32->bf16
  unsigned int x = __float_as_uint(f);
  x += 0x7fffu + ((x >> 16) & 1u);
  return (unsigned short)(x >> 16);
}
__device__ __forceinline__ float bf2f(unsigned short u) {
  return __uint_as_float(((unsigned int)u) << 16);
}
__device__ __forceinline__ void gld16(const void* g, void* l) {
  __builtin_amdgcn_global_load_lds((const __attribute__((address_space(1))) void*)g,
                                   (__attribute__((address_space(3))) void*)l, 16, 0, 0);
}
__device__ __forceinline__ unsigned int cvtpk(float a, float b) {  // bf16(a) | bf16(b)<<16
  unsigned int r;
  asm("v_cvt_pk_bf16_f32 %0, %1, %2" : "=v"(r) : "v"(a), "v"(b));
  return r;
}

// ---------------- rope table: [s][j] -> (cos, sin), j<32 ----------------
__global__ __launch_bounds__(256) void ropetab_k(float2* tab) {
  int i = blockIdx.x * 256 + threadIdx.x;       // 2048*32 = 65536
  int s = i >> 5, j = i & 31;
  float inv = exp2f(-(float)j * (13.287712379549449f / 32.0f));
  float ang = (float)s * inv;
  tab[i] = make_float2(cosf(ang), sinf(ang));
}

// ---------------- x f32 -> bf16 ----------------
__global__ __launch_bounds__(256) void cvtx_k(const float4* __restrict__ x, ushort4* __restrict__ xb) {
  int i = blockIdx.x * 256 + threadIdx.x;       // 2097152
  float4 f = x[i];
  ushort4 o;
  o.x = f2bfu(f.x); o.y = f2bfu(f.y); o.z = f2bfu(f.z); o.w = f2bfu(f.w);
  xb[i] = o;
}

// ---------------- weight transpose+cvt: in f32 [2048][N] -> out bf16 [N][2048] ----------------
__global__ __launch_bounds__(256) void wtrans_k(const float* __restrict__ in, unsigned short* __restrict__ out, int N) {
  __shared__ float tile[32][33];
  int n0 = blockIdx.x * 32, k0 = blockIdx.y * 32;
  int tx = threadIdx.x, ty = threadIdx.y;       // 32 x 8
#pragma unroll
  for (int i = 0; i < 4; ++i)
    tile[ty + 8*i][tx] = in[(size_t)(k0 + ty + 8*i) * N + n0 + tx];
  __syncthreads();
#pragma unroll
  for (int i = 0; i < 4; ++i)
    out[(size_t)(n0 + ty + 8*i) * 2048 + k0 + tx] = f2bfu(tile[tx][ty + 8*i]);
}

// ---------------- GEMM: C[M][N] = A[M][K] * Bt[N][K]^T  (bf16 in, f32 acc) ----------------
template<int OUTF32>
__global__ __launch_bounds__(256) void gemm_bt(const unsigned short* __restrict__ A,
                                               const unsigned short* __restrict__ Bt,
                                               void* __restrict__ Cout, int M, int N, int K) {
  __shared__ unsigned short Al[2][128][32];
  __shared__ unsigned short Bl[2][128][32];
  int tid = threadIdx.x, lane = tid & 63, w = tid >> 6;
  int lr = lane & 15, lg = lane >> 4;
  int wr = w >> 1, wc = w & 1;
  int m0 = blockIdx.y * 128, n0 = blockIdx.x * 128;
  int trow = tid >> 2, tseg = tid & 3;

  auto stage = [&](int buf, int kt) {
    const unsigned short* ga0 = A + (size_t)(m0 + trow) * K + kt * 32 + tseg * 8;
    gld16(ga0, &Al[buf][trow][tseg * 8]);
    const unsigned short* ga1 = A + (size_t)(m0 + 64 + trow) * K + kt * 32 + tseg * 8;
    gld16(ga1, &Al[buf][64 + trow][tseg * 8]);
    const unsigned short* gb0 = Bt + (size_t)(n0 + trow) * K + kt * 32 + tseg * 8;
    gld16(gb0, &Bl[buf][trow][tseg * 8]);
    const unsigned short* gb1 = Bt + (size_t)(n0 + 64 + trow) * K + kt * 32 + tseg * 8;
    gld16(gb1, &Bl[buf][64 + trow][tseg * 8]);
  };

  f32x4 zero4 = {0.f, 0.f, 0.f, 0.f};
  f32x4 acc[4][4];
#pragma unroll
  for (int mi = 0; mi < 4; ++mi)
#pragma unroll
    for (int ni = 0; ni < 4; ++ni) acc[mi][ni] = zero4;

  int nk = K >> 5;
  stage(0, 0);
  int buf = 0;
  for (int kt = 0; kt < nk; ++kt) {
    __syncthreads();
    if (kt + 1 < nk) stage(buf ^ 1, kt + 1);
    short8 af[4], bfr[4];
#pragma unroll
    for (int i = 0; i < 4; ++i) {
      af[i]  = *(const short8*)&Al[buf][64 * wr + 16 * i + lr][lg * 8];
      bfr[i] = *(const short8*)&Bl[buf][64 * wc + 16 * i + lr][lg * 8];
    }
#pragma unroll
    for (int mi = 0; mi < 4; ++mi)
#pragma unroll
      for (int ni = 0; ni < 4; ++ni)
        acc[mi][ni] = __builtin_amdgcn_mfma_f32_16x16x32_bf16(af[mi], bfr[ni], acc[mi][ni], 0, 0, 0);
    buf ^= 1;
  }
#pragma unroll
  for (int mi = 0; mi < 4; ++mi)
#pragma unroll
    for (int ni = 0; ni < 4; ++ni)
#pragma unroll
      for (int r = 0; r < 4; ++r) {
        int row = m0 + 64 * wr + 16 * mi + lg * 4 + r;
        int col = n0 + 64 * wc + 16 * ni + lr;
        float v = acc[mi][ni][r];
        if (OUTF32) ((float*)Cout)[(size_t)row * N + col] = v;
        else ((unsigned short*)Cout)[(size_t)row * N + col] = f2bfu(v);
      }
}

// ---------------- RoPE in-place on q,k columns of qkv ----------------
__global__ __launch_bounds__(256) void rope_k(unsigned short* __restrict__ qkv, const float2* __restrict__ tab) {
  int idx = blockIdx.x * 256 + threadIdx.x;
  int tok = idx / 1280, r = idx % 1280;
  int col, j;
  if (r < 1024) { j = r & 31; col = (r >> 5) * 64 + j; }
  else { int rr = r - 1024; j = rr & 31; col = 2048 + (rr >> 5) * 64 + j; }
  int s = tok & (S_ - 1);
  float2 cs = tab[s * 32 + j];
  unsigned short* p = qkv + (size_t)tok * NQKV_ + col;
  float a = bf2f(p[0]), b = bf2f(p[32]);
  p[0]  = f2bfu(a * cs.x - b * cs.y);
  p[32] = f2bfu(b * cs.x + a * cs.y);
}

// ---------------- V -> V^T relayout ----------------
__global__ __launch_bounds__(256) void vtrans_k(const unsigned short* __restrict__ qkv, unsigned short* __restrict__ vt) {
  __shared__ unsigned short tile[32][33];
  int s0 = blockIdx.x * 32;
  int y0 = blockIdx.y * 32;
  int bkv = y0 >> 6, d0 = y0 & 63;
  int b = bkv >> 3, kv = bkv & 7;
  int tx = threadIdx.x, ty = threadIdx.y;
#pragma unroll
  for (int i = 0; i < 4; ++i)
    tile[ty + 8*i][tx] = qkv[(size_t)(b * S_ + s0 + ty + 8*i) * NQKV_ + 2560 + kv * 64 + d0 + tx];
  __syncthreads();
#pragma unroll
  for (int i = 0; i < 4; ++i)
    vt[(size_t)(y0 + ty + 8*i) * (size_t)S_ + s0 + tx] = tile[tx][ty + 8*i];
}

// ---------------- flash attention (swapped QK^T + XOR-swizzled LDS) ----------------
// grid (B*H=64, S/64=32); 256 thr = 4 waves, wave w owns q-rows [q0+16w, q0+16w+16)
// LDS swizzle: 16B slot index ^= (row&7); staged via pre-swizzled GLOBAL source col (rule 21).
#define RLOG 0.1803368801111179f   // 0.125 * log2(e) -- folds the 1/sqrt(64) scale into exp2
__global__ __launch_bounds__(256) void attn_k(const unsigned short* __restrict__ qkv,
                                              const unsigned short* __restrict__ vt,
                                              unsigned short* __restrict__ ao) {
  __shared__ unsigned short Kl[2][64][64];   // [key][d], swizzled
  __shared__ unsigned short Vl[2][64][64];   // V^T: [d][key], swizzled
  __shared__ unsigned short Pl[64][64];      // [q(16w+lr)][key], swizzled, wave-private rows
  int bh = blockIdx.x, b = bh >> 5, h = bh & 31, kvh = h >> 2;
  int q0 = blockIdx.y * 64;
  int tid = threadIdx.x, w = tid >> 6, lane = tid & 63;
  int lr = lane & 15, lg = lane >> 4;
  int sw = lr & 7;                            // read-side swizzle key (row&7 for all frag reads)

  // Q fragments (reused as B-operand of swapped QK; B-frag lane layout == A-frag layout)
  const unsigned short* qp = qkv + (size_t)(b * S_ + q0 + 16 * w + lr) * NQKV_ + h * 64 + lg * 8;
  short8 qa0 = *(const short8*)qp;
  short8 qa1 = *(const short8*)(qp + 32);

  const unsigned short* kbase = qkv + (size_t)(b * S_) * NQKV_ + 2048 + kvh * 64;
  const unsigned short* vbase = vt + (size_t)(b * KV_ + kvh) * 64 * S_;
  int srow = tid >> 3, sseg = tid & 7;        // 32 rows x 8 slots of 16B per shot
  int scol = (sseg ^ (srow & 7)) * 8;         // pre-swizzled global source column

  auto stageKV = [&](int buf, int kv0) {
#pragma unroll
    for (int sh = 0; sh < 2; ++sh) {
      gld16(kbase + (size_t)(kv0 + 32 * sh + srow) * NQKV_ + scol, &Kl[buf][32 * sh + srow][sseg * 8]);
      gld16(vbase + (size_t)(32 * sh + srow) * S_ + kv0 + scol, &Vl[buf][32 * sh + srow][sseg * 8]);
    }
  };

  f32x4 zero4 = {0.f, 0.f, 0.f, 0.f};
  f32x4 o[4];
  float rmax = -1e30f, rsum = 0.f;            // softmax state for q = q0+16w+lr
#pragma unroll
  for (int i = 0; i < 4; ++i) o[i] = zero4;

  stageKV(0, 0);
  int buf = 0;
  for (int it = 0; it < S_ / 64; ++it) {
    __syncthreads();
    if (it + 1 < S_ / 64) stageKV(buf ^ 1, (it + 1) * 64);

    // --- S^T = K Q^T : sc[c][r] = S[q=lr][key=16c+4lg+r] (raw, unscaled) ---
    f32x4 sc[4];
#pragma unroll
    for (int c = 0; c < 4; ++c) {
      const unsigned short* krow = &Kl[buf][16 * c + lr][0];
      short8 kb0 = *(const short8*)(krow + (lg ^ sw) * 8);
      short8 kb1 = *(const short8*)(krow + ((4 + lg) ^ sw) * 8);
      f32x4 z = zero4;
      z = __builtin_amdgcn_mfma_f32_16x16x32_bf16(kb0, qa0, z, 0, 0, 0);
      z = __builtin_amdgcn_mfma_f32_16x16x32_bf16(kb1, qa1, z, 0, 0, 0);
      sc[c] = z;
    }

    // --- online softmax for q=lr: 15 in-lane fmax + 2 shfl ---
    float ml = sc[0][0];
#pragma unroll
    for (int c = 0; c < 4; ++c)
#pragma unroll
      for (int r = 0; r < 4; ++r) ml = fmaxf(ml, sc[c][r]);
    ml = fmaxf(ml, __shfl_xor(ml, 16));
    ml = fmaxf(ml, __shfl_xor(ml, 32));
    float mn = fmaxf(rmax, ml);
    float corr = exp2f((rmax - mn) * RLOG);
    rmax = mn;
    float mk = mn * RLOG;
    float p[4][4];
    float rs = 0.f;
#pragma unroll
    for (int c = 0; c < 4; ++c)
#pragma unroll
      for (int r = 0; r < 4; ++r) {
        float pv = exp2f(sc[c][r] * RLOG - mk);
        p[c][r] = pv;
        rs += pv;
      }
    rs += __shfl_xor(rs, 16);
    rs += __shfl_xor(rs, 32);
    rsum = rsum * corr + rs;

    // --- rescale O (rows q=4lg+r): broadcast corr from lane 4lg+r ---
    float co[4];
#pragma unroll
    for (int r = 0; r < 4; ++r) co[r] = __shfl(corr, 4 * lg + r);
#pragma unroll
    for (int dt = 0; dt < 4; ++dt)
#pragma unroll
      for (int r = 0; r < 4; ++r) o[dt][r] *= co[r];

    // --- P -> LDS: 4x packed ds_write_b64, swizzled; rows wave-private ---
    char* prow = (char*)Pl + (16 * w + lr) * 128;
#pragma unroll
    for (int c = 0; c < 4; ++c) {
      uint2 uu;
      uu.x = cvtpk(p[c][0], p[c][1]);
      uu.y = cvtpk(p[c][2], p[c][3]);
      int slot = (2 * c + (lg >> 1)) ^ sw;
      *(uint2*)(prow + slot * 16 + 8 * (lg & 1)) = uu;
    }

    // --- O += P V : A = P rows q, B = V^T rows d ---
    const char* parow = (const char*)Pl + (16 * w + lr) * 128;
    short8 pa0 = *(const short8*)(parow + (lg ^ sw) * 16);
    short8 pa1 = *(const short8*)(parow + ((4 + lg) ^ sw) * 16);
#pragma unroll
    for (int dt = 0; dt < 4; ++dt) {
      const unsigned short* vrow = &Vl[buf][16 * dt + lr][0];
      short8 vb0 = *(const short8*)(vrow + (lg ^ sw) * 8);
      short8 vb1 = *(const short8*)(vrow + ((4 + lg) ^ sw) * 8);
      o[dt] = __builtin_amdgcn_mfma_f32_16x16x32_bf16(pa0, vb0, o[dt], 0, 0, 0);
      o[dt] = __builtin_amdgcn_mfma_f32_16x16x32_bf16(pa1, vb1, o[dt], 0, 0, 0);
    }
    buf ^= 1;
  }

  // --- epilogue: O[q=4lg+r][d=16dt+lr] / rowsum -> ao[b][s][h][d] ---
  float rsO[4];
#pragma unroll
  for (int r = 0; r < 4; ++r) rsO[r] = __shfl(rsum, 4 * lg + r);
#pragma unroll
  for (int r = 0; r < 4; ++r) {
    float inv = 1.f / rsO[r];
    int row = q0 + 16 * w + 4 * lg + r;
#pragma unroll
    for (int dt = 0; dt < 4; ++dt)
      ao[(size_t)(b * S_ + row) * D_ + h * 64 + 16 * dt + lr] = f2bfu(o[dt][r] * inv);
  }
}

// ---------------- launch ----------------
extern "C" void kernel_launch(void* const* d_in, const int* in_sizes, int n_in,
                              void* d_out, int out_size, void* d_ws, size_t ws_size,
                              hipStream_t stream) {
  const float* x  = (const float*)d_in[0];
  const float* Wq = (const float*)d_in[1];
  const float* Wk = (const float*)d_in[2];
  const float* Wv = (const float*)d_in[3];
  const float* Wo = (const float*)d_in[4];

  char* ws = (char*)d_ws;
  unsigned short* xb    = (unsigned short*)(ws + OFF_XB);
  unsigned short* wqkvt = (unsigned short*)(ws + OFF_WQKV);
  unsigned short* wot   = (unsigned short*)(ws + OFF_WO);
  unsigned short* qkv   = (unsigned short*)(ws + OFF_QKV);
  unsigned short* vt    = (unsigned short*)(ws + OFF_VT);
  unsigned short* ao    = (unsigned short*)(ws + OFF_AO);
  float2*         tab   = (float2*)(ws + OFF_TAB);

  ropetab_k<<<dim3(256), dim3(256), 0, stream>>>(tab);
  cvtx_k<<<dim3((TOK_*D_/4)/256), dim3(256), 0, stream>>>((const float4*)x, (ushort4*)xb);
  wtrans_k<<<dim3(64, 64), dim3(32, 8), 0, stream>>>(Wq, wqkvt, 2048);
  wtrans_k<<<dim3(16, 64), dim3(32, 8), 0, stream>>>(Wk, wqkvt + (size_t)2048 * 2048, 512);
  wtrans_k<<<dim3(16, 64), dim3(32, 8), 0, stream>>>(Wv, wqkvt + (size_t)2560 * 2048, 512);
  wtrans_k<<<dim3(64, 64), dim3(32, 8), 0, stream>>>(Wo, wot, 2048);

  gemm_bt<0><<<dim3(NQKV_/128, TOK_/128), dim3(256), 0, stream>>>(xb, wqkvt, (void*)qkv, TOK_, NQKV_, D_);
  rope_k<<<dim3(TOK_ * 1280 / 256), dim3(256), 0, stream>>>(qkv, tab);
  vtrans_k<<<dim3(S_/32, (B_*KV_*HD_)/32), dim3(32, 8), 0, stream>>>(qkv, vt);
  attn_k<<<dim3(B_*H_, S_/64), dim3(256), 0, stream>>>(qkv, vt, ao);
  gemm_bt<1><<<dim3(D_/128, TOK_/128), dim3(256), 0, stream>>>(ao, wot, d_out, TOK_, D_, D_);
}

// Round 4
// 292.354 us; speedup vs baseline: 1.4737x; 1.0501x over previous
//
#include <hip/hip_runtime.h>

// ---------------- problem constants ----------------
#define B_   2
#define S_   2048
#define D_   2048
#define H_   32
#define KV_  8
#define HD_  64
#define TOK_ (B_*S_)   // 4096
#define NQKV_ 3072     // 2048 q + 512 k + 512 v

typedef __attribute__((ext_vector_type(8))) short short8;
typedef __attribute__((ext_vector_type(4))) float f32x4;
typedef __attribute__((ext_vector_type(16))) float f32x16;

// ---------------- ws layout (bytes) ----------------
#define OFF_XB   ((size_t)0)
#define OFF_WQKV (OFF_XB   + (size_t)TOK_*D_*2)
#define OFF_WO   (OFF_WQKV + (size_t)NQKV_*D_*2)
#define OFF_QKV  (OFF_WO   + (size_t)D_*D_*2)
#define OFF_VT   (OFF_QKV  + (size_t)TOK_*NQKV_*2)
#define OFF_AO   (OFF_VT   + (size_t)B_*KV_*HD_*S_*2)
#define OFF_TAB  (OFF_AO   + (size_t)TOK_*D_*2)

__device__ __forceinline__ unsigned short f2bfu(float f) {
  unsigned int x = __float_as_uint(f);
  x += 0x7fffu + ((x >> 16) & 1u);
  return (unsigned short)(x >> 16);
}
__device__ __forceinline__ float bf2f(unsigned short u) {
  return __uint_as_float(((unsigned int)u) << 16);
}
__device__ __forceinline__ unsigned int pk2(float a, float b) {  // [bf16(a) | bf16(b)<<16]
  return (unsigned int)f2bfu(a) | ((unsigned int)f2bfu(b) << 16);
}
__device__ __forceinline__ void gld16(const void* g, void* l) {
  __builtin_amdgcn_global_load_lds((const __attribute__((address_space(1))) void*)g,
                                   (__attribute__((address_space(3))) void*)l, 16, 0, 0);
}

// ---------------- rope table ----------------
__global__ __launch_bounds__(256) void ropetab_k(float2* tab) {
  int i = blockIdx.x * 256 + threadIdx.x;
  int s = i >> 5, j = i & 31;
  float inv = exp2f(-(float)j * (13.287712379549449f / 32.0f));
  float ang = (float)s * inv;
  tab[i] = make_float2(cosf(ang), sinf(ang));
}

// ---------------- x f32 -> bf16 ----------------
__global__ __launch_bounds__(256) void cvtx_k(const float4* __restrict__ x, ushort4* __restrict__ xb) {
  int i = blockIdx.x * 256 + threadIdx.x;
  float4 f = x[i];
  ushort4 o;
  o.x = f2bfu(f.x); o.y = f2bfu(f.y); o.z = f2bfu(f.z); o.w = f2bfu(f.w);
  xb[i] = o;
}

// ---------------- weight transpose+cvt ----------------
__global__ __launch_bounds__(256) void wtrans_k(const float* __restrict__ in, unsigned short* __restrict__ out, int N) {
  __shared__ float tile[32][33];
  int n0 = blockIdx.x * 32, k0 = blockIdx.y * 32;
  int tx = threadIdx.x, ty = threadIdx.y;
#pragma unroll
  for (int i = 0; i < 4; ++i)
    tile[ty + 8*i][tx] = in[(size_t)(k0 + ty + 8*i) * N + n0 + tx];
  __syncthreads();
#pragma unroll
  for (int i = 0; i < 4; ++i)
    out[(size_t)(n0 + ty + 8*i) * 2048 + k0 + tx] = f2bfu(tile[tx][ty + 8*i]);
}

// ---------------- GEMM (unchanged from R1, passed) ----------------
template<int OUTF32>
__global__ __launch_bounds__(256) void gemm_bt(const unsigned short* __restrict__ A,
                                               const unsigned short* __restrict__ Bt,
                                               void* __restrict__ Cout, int M, int N, int K) {
  __shared__ unsigned short Al[2][128][32];
  __shared__ unsigned short Bl[2][128][32];
  int tid = threadIdx.x, lane = tid & 63, w = tid >> 6;
  int lr = lane & 15, lg = lane >> 4;
  int wr = w >> 1, wc = w & 1;
  int m0 = blockIdx.y * 128, n0 = blockIdx.x * 128;
  int trow = tid >> 2, tseg = tid & 3;

  auto stage = [&](int buf, int kt) {
    gld16(A + (size_t)(m0 + trow) * K + kt * 32 + tseg * 8, &Al[buf][trow][tseg * 8]);
    gld16(A + (size_t)(m0 + 64 + trow) * K + kt * 32 + tseg * 8, &Al[buf][64 + trow][tseg * 8]);
    gld16(Bt + (size_t)(n0 + trow) * K + kt * 32 + tseg * 8, &Bl[buf][trow][tseg * 8]);
    gld16(Bt + (size_t)(n0 + 64 + trow) * K + kt * 32 + tseg * 8, &Bl[buf][64 + trow][tseg * 8]);
  };

  f32x4 zero4 = {0.f, 0.f, 0.f, 0.f};
  f32x4 acc[4][4];
#pragma unroll
  for (int mi = 0; mi < 4; ++mi)
#pragma unroll
    for (int ni = 0; ni < 4; ++ni) acc[mi][ni] = zero4;

  int nk = K >> 5;
  stage(0, 0);
  int buf = 0;
  for (int kt = 0; kt < nk; ++kt) {
    __syncthreads();
    if (kt + 1 < nk) stage(buf ^ 1, kt + 1);
    short8 af[4], bfr[4];
#pragma unroll
    for (int i = 0; i < 4; ++i) {
      af[i]  = *(const short8*)&Al[buf][64 * wr + 16 * i + lr][lg * 8];
      bfr[i] = *(const short8*)&Bl[buf][64 * wc + 16 * i + lr][lg * 8];
    }
#pragma unroll
    for (int mi = 0; mi < 4; ++mi)
#pragma unroll
      for (int ni = 0; ni < 4; ++ni)
        acc[mi][ni] = __builtin_amdgcn_mfma_f32_16x16x32_bf16(af[mi], bfr[ni], acc[mi][ni], 0, 0, 0);
    buf ^= 1;
  }
#pragma unroll
  for (int mi = 0; mi < 4; ++mi)
#pragma unroll
    for (int ni = 0; ni < 4; ++ni)
#pragma unroll
      for (int r = 0; r < 4; ++r) {
        int row = m0 + 64 * wr + 16 * mi + lg * 4 + r;
        int col = n0 + 64 * wc + 16 * ni + lr;
        float v = acc[mi][ni][r];
        if (OUTF32) ((float*)Cout)[(size_t)row * N + col] = v;
        else ((unsigned short*)Cout)[(size_t)row * N + col] = f2bfu(v);
      }
}

// ---------------- RoPE in-place ----------------
__global__ __launch_bounds__(256) void rope_k(unsigned short* __restrict__ qkv, const float2* __restrict__ tab) {
  int idx = blockIdx.x * 256 + threadIdx.x;
  int tok = idx / 1280, r = idx % 1280;
  int col, j;
  if (r < 1024) { j = r & 31; col = (r >> 5) * 64 + j; }
  else { int rr = r - 1024; j = rr & 31; col = 2048 + (rr >> 5) * 64 + j; }
  int s = tok & (S_ - 1);
  float2 cs = tab[s * 32 + j];
  unsigned short* p = qkv + (size_t)tok * NQKV_ + col;
  float a = bf2f(p[0]), b = bf2f(p[32]);
  p[0]  = f2bfu(a * cs.x - b * cs.y);
  p[32] = f2bfu(b * cs.x + a * cs.y);
}

// ---------------- V -> V^T relayout ----------------
__global__ __launch_bounds__(256) void vtrans_k(const unsigned short* __restrict__ qkv, unsigned short* __restrict__ vt) {
  __shared__ unsigned short tile[32][33];
  int s0 = blockIdx.x * 32;
  int y0 = blockIdx.y * 32;
  int bkv = y0 >> 6, d0 = y0 & 63;
  int b = bkv >> 3, kv = bkv & 7;
  int tx = threadIdx.x, ty = threadIdx.y;
#pragma unroll
  for (int i = 0; i < 4; ++i)
    tile[ty + 8*i][tx] = qkv[(size_t)(b * S_ + s0 + ty + 8*i) * NQKV_ + 2560 + kv * 64 + d0 + tx];
  __syncthreads();
#pragma unroll
  for (int i = 0; i < 4; ++i)
    vt[(size_t)(y0 + ty + 8*i) * (size_t)S_ + s0 + tx] = tile[tx][ty + 8*i];
}

// ---------------- flash attention: 32x32 MFMA, in-register softmax, defer-max ----------------
// grid (B*H=64, S/128=16); 256 thr = 4 waves, wave w owns q-rows [q0+32w, q0+32w+32)
// S^T = mfma(A=K rows, B=Q rows): lane holds S[key crow][q=lane&31]
// C/D layout (m74): col=lane&31, row=(reg&3)+8*(reg>>2)+4*(lane>>5)
// BISECT vs R2: all cross-lane/pack ops via R1-verified primitives (__shfl_xor, f2bfu);
// no v_permlane32_swap_b32, no v_cvt_pk_bf16_f32.
#define RLOG 0.1803368801111179f   // 0.125 * log2(e)
#define THRRAW 44.0f               // defer-max threshold (raw-score units): 8 / RLOG
__global__ __launch_bounds__(256, 4) void attn_k(const unsigned short* __restrict__ qkv,
                                                 const unsigned short* __restrict__ vt,
                                                 unsigned short* __restrict__ ao) {
  __shared__ unsigned short Kl[2][64][64];   // [key][d], XOR-swizzled 16B slots
  __shared__ unsigned short Vl[2][64][64];   // V^T [d][key], XOR-swizzled
  int bh = blockIdx.x, b = bh >> 5, h = bh & 31, kvh = h >> 2;
  int q0 = blockIdx.y * 128;
  int tid = threadIdx.x, w = tid >> 6, lane = tid & 63;
  int lq = lane & 31, hf = lane >> 5;
  int swk = lq & 7;                          // read swizzle key (= row&7 for rows ks*32+lq)

  // Q fragments: B-operand, col=q=lane&31, k(d) = kst*16 + hf*8 + j
  const unsigned short* qp = qkv + (size_t)(b * S_ + q0 + w * 32 + lq) * NQKV_ + h * 64 + hf * 8;
  short8 qf[4];
#pragma unroll
  for (int k = 0; k < 4; ++k) qf[k] = *(const short8*)(qp + k * 16);

  const unsigned short* kbase = qkv + (size_t)(b * S_) * NQKV_ + 2048 + kvh * 64;
  const unsigned short* vbase = vt + (size_t)(b * KV_ + kvh) * 64 * S_;
  int srow = tid >> 3, sslot = tid & 7;
  int scol = (sslot ^ (srow & 7)) * 8;       // pre-swizzled global source column

  auto stageKV = [&](int buf, int kv0) {
#pragma unroll
    for (int sh = 0; sh < 2; ++sh) {
      gld16(kbase + (size_t)(kv0 + 32 * sh + srow) * NQKV_ + scol, &Kl[buf][32 * sh + srow][sslot * 8]);
      gld16(vbase + (size_t)(32 * sh + srow) * S_ + kv0 + scol, &Vl[buf][32 * sh + srow][sslot * 8]);
    }
  };

  f32x16 O0, O1;
#pragma unroll
  for (int r = 0; r < 16; ++r) { O0[r] = 0.f; O1[r] = 0.f; }
  float rmax = -1e30f, rsum = 0.f;           // softmax state for q = q0+32w+lq

  stageKV(0, 0);
  int buf = 0;
  for (int it = 0; it < S_ / 64; ++it) {
    __syncthreads();
    if (it + 1 < S_ / 64) stageKV(buf ^ 1, (it + 1) * 64);

    // --- S^T = K Q^T (raw scores) ---
    f32x16 sa, sb;
#pragma unroll
    for (int r = 0; r < 16; ++r) { sa[r] = 0.f; sb[r] = 0.f; }
#pragma unroll
    for (int kst = 0; kst < 4; ++kst) {
      short8 kf = *(const short8*)&Kl[buf][lq][((kst * 2 + hf) ^ swk) * 8];
      sa = __builtin_amdgcn_mfma_f32_32x32x16_bf16(kf, qf[kst], sa, 0, 0, 0);
    }
#pragma unroll
    for (int kst = 0; kst < 4; ++kst) {
      short8 kf = *(const short8*)&Kl[buf][32 + lq][((kst * 2 + hf) ^ swk) * 8];
      sb = __builtin_amdgcn_mfma_f32_32x32x16_bf16(kf, qf[kst], sb, 0, 0, 0);
    }

    // --- tile max for q=lane&31 (31 in-lane fmax + cross-half shfl) ---
    float pm = sa[0];
#pragma unroll
    for (int r = 1; r < 16; ++r) pm = fmaxf(pm, sa[r]);
#pragma unroll
    for (int r = 0; r < 16; ++r) pm = fmaxf(pm, sb[r]);
    pm = fmaxf(pm, __shfl_xor(pm, 32));

    // --- defer-max: rescale only when growth exceeds threshold ---
    if (!__all(pm - rmax <= THRRAW)) {
      float mn = fmaxf(rmax, pm);
      float corr = exp2f((rmax - mn) * RLOG);
      rmax = mn;
      rsum *= corr;
      float co[16];
#pragma unroll
      for (int r = 0; r < 16; ++r) co[r] = __shfl(corr, (r & 3) + 8 * (r >> 2) + 4 * hf);
#pragma unroll
      for (int r = 0; r < 16; ++r) { O0[r] *= co[r]; O1[r] *= co[r]; }
    }

    // --- P = exp2(S*RLOG - mk), row sum ---
    float mk = rmax * RLOG;
    float rs = 0.f;
#pragma unroll
    for (int r = 0; r < 16; ++r) { float p = exp2f(sa[r] * RLOG - mk); sa[r] = p; rs += p; }
#pragma unroll
    for (int r = 0; r < 16; ++r) { float p = exp2f(sb[r] * RLOG - mk); sb[r] = p; rs += p; }
    rs += __shfl_xor(rs, 32);
    rsum += rs;

    // --- PV: build P A-fragments with pk2 + shfl_xor(32) + hf-select ---
    // lane needs P[q=lq][key = base16 + hf*8 + j]; own regs hold keys crow(r,hf).
    // hf=0 words: {own(0,1),(2,3), partner(4,5),(6,7)}; hf=1: {partner(8,9),(10,11), own(12,13),(14,15)}
    auto pv_sub = [&](const f32x16& sc, int ks) {
#pragma unroll
      for (int k16 = 0; k16 < 2; ++k16) {
        unsigned int c01 = pk2(sc[k16 * 8 + 0], sc[k16 * 8 + 1]);
        unsigned int c23 = pk2(sc[k16 * 8 + 2], sc[k16 * 8 + 3]);
        unsigned int c45 = pk2(sc[k16 * 8 + 4], sc[k16 * 8 + 5]);
        unsigned int c67 = pk2(sc[k16 * 8 + 6], sc[k16 * 8 + 7]);
        unsigned int x01 = __shfl_xor(c01, 32);
        unsigned int x23 = __shfl_xor(c23, 32);
        unsigned int x45 = __shfl_xor(c45, 32);
        unsigned int x67 = __shfl_xor(c67, 32);
        union { unsigned int u[4]; short8 s8; } pu;
        pu.u[0] = hf ? x45 : c01;
        pu.u[1] = hf ? x67 : c23;
        pu.u[2] = hf ? c45 : x01;
        pu.u[3] = hf ? c67 : x23;
        int kk = ks * 2 + k16;               // 16-key step within 64-key tile
        short8 v0 = *(const short8*)&Vl[buf][lq][((kk * 2 + hf) ^ swk) * 8];
        O0 = __builtin_amdgcn_mfma_f32_32x32x16_bf16(pu.s8, v0, O0, 0, 0, 0);
        short8 v1 = *(const short8*)&Vl[buf][32 + lq][((kk * 2 + hf) ^ swk) * 8];
        O1 = __builtin_amdgcn_mfma_f32_32x32x16_bf16(pu.s8, v1, O1, 0, 0, 0);
      }
    };
    pv_sub(sa, 0);
    pv_sub(sb, 1);
    buf ^= 1;
  }

  // --- epilogue: O[q=crow][d] / rsum -> ao[b][s][h*64+d] ---
  float inv = 1.f / rsum;
#pragma unroll
  for (int r = 0; r < 16; ++r) {
    int qr = (r & 3) + 8 * (r >> 2) + 4 * hf;
    float io = __shfl(inv, qr);
    size_t row = (size_t)(b * S_ + q0 + w * 32 + qr);
    ao[row * D_ + h * 64 + lq]      = f2bfu(O0[r] * io);
    ao[row * D_ + h * 64 + 32 + lq] = f2bfu(O1[r] * io);
  }
}

// ---------------- launch ----------------
extern "C" void kernel_launch(void* const* d_in, const int* in_sizes, int n_in,
                              void* d_out, int out_size, void* d_ws, size_t ws_size,
                              hipStream_t stream) {
  const float* x  = (const float*)d_in[0];
  const float* Wq = (const float*)d_in[1];
  const float* Wk = (const float*)d_in[2];
  const float* Wv = (const float*)d_in[3];
  const float* Wo = (const float*)d_in[4];

  char* ws = (char*)d_ws;
  unsigned short* xb    = (unsigned short*)(ws + OFF_XB);
  unsigned short* wqkvt = (unsigned short*)(ws + OFF_WQKV);
  unsigned short* wot   = (unsigned short*)(ws + OFF_WO);
  unsigned short* qkv   = (unsigned short*)(ws + OFF_QKV);
  unsigned short* vt    = (unsigned short*)(ws + OFF_VT);
  unsigned short* ao    = (unsigned short*)(ws + OFF_AO);
  float2*         tab   = (float2*)(ws + OFF_TAB);

  ropetab_k<<<dim3(256), dim3(256), 0, stream>>>(tab);
  cvtx_k<<<dim3((TOK_*D_/4)/256), dim3(256), 0, stream>>>((const float4*)x, (ushort4*)xb);
  wtrans_k<<<dim3(64, 64), dim3(32, 8), 0, stream>>>(Wq, wqkvt, 2048);
  wtrans_k<<<dim3(16, 64), dim3(32, 8), 0, stream>>>(Wk, wqkvt + (size_t)2048 * 2048, 512);
  wtrans_k<<<dim3(16, 64), dim3(32, 8), 0, stream>>>(Wv, wqkvt + (size_t)2560 * 2048, 512);
  wtrans_k<<<dim3(64, 64), dim3(32, 8), 0, stream>>>(Wo, wot, 2048);

  gemm_bt<0><<<dim3(NQKV_/128, TOK_/128), dim3(256), 0, stream>>>(xb, wqkvt, (void*)qkv, TOK_, NQKV_, D_);
  rope_k<<<dim3(TOK_ * 1280 / 256), dim3(256), 0, stream>>>(qkv, tab);
  vtrans_k<<<dim3(S_/32, (B_*KV_*HD_)/32), dim3(32, 8), 0, stream>>>(qkv, vt);
  attn_k<<<dim3(B_*H_, S_/128), dim3(256), 0, stream>>>(qkv, vt, ao);
  gemm_bt<1><<<dim3(D_/128, TOK_/128), dim3(256), 0, stream>>>(ao, wot, d_out, TOK_, D_, D_);
}